// Round 2
// baseline (538.578 us; speedup 1.0000x reference)
//
#include <hip/hip_runtime.h>

// Conv2d 3x3 s1 p1, B=16, CIN=COUT=64, 112x112, fp32 direct conv.
// Thread tile: 8 couts x 4 consecutive-w pixels. Block = 256 threads.
// grid = (B*H*W/(256*4) = 196, COUT/8 = 8). Weights [576][8] staged in LDS.
// (Resubmission — round 0/1 never acquired a GPU; no counters yet.)

#define BATCH 16
#define CIN   64
#define HH    112
#define WW    112
#define COUT  64
#define CO_TILE 8
#define PIX   4

__global__ __launch_bounds__(256) void conv3x3_f32_kernel(
    const float* __restrict__ x, const float* __restrict__ weight,
    const float* __restrict__ bias, float* __restrict__ out) {
  __shared__ float sW[576 * CO_TILE];  // [k = c*9+kh*3+kw][co]

  const int tid = threadIdx.x;
  const int cobase = blockIdx.y * CO_TILE;

  // Stage this block's weight slice: sW[k*8+co] = weight[k*64 + cobase+co]
  for (int i = tid; i < 576 * CO_TILE; i += 256) {
    int k = i >> 3, co = i & 7;
    sW[i] = weight[k * COUT + cobase + co];
  }
  __syncthreads();

  // Flat pixel index; 4 consecutive w per thread (112 % 4 == 0 -> same row)
  int p = (blockIdx.x * 256 + tid) * PIX;
  int b = p / (HH * WW);
  int rem = p - b * (HH * WW);
  int h = rem / WW;
  int w = rem - h * WW;

  const float* xb = x + (size_t)b * CIN * HH * WW;

  // Clamped row offsets + row validity masks (uniform per thread)
  int roff[3];
  float rm[3];
#pragma unroll
  for (int kh = 0; kh < 3; ++kh) {
    int row = h + kh - 1;
    int rc = row < 0 ? 0 : (row > HH - 1 ? HH - 1 : row);
    roff[kh] = rc * WW;
    rm[kh] = (row >= 0 && row < HH) ? 1.f : 0.f;
  }
  // Clamped column offsets + combined masks. cols w-1 .. w+4 (6 values)
  int coff[6];
  float m[3][6];
#pragma unroll
  for (int t = 0; t < 6; ++t) {
    int col = w - 1 + t;
    int cc = col < 0 ? 0 : (col > WW - 1 ? WW - 1 : col);
    coff[t] = cc;
    float cmask = (col >= 0 && col < WW) ? 1.f : 0.f;
#pragma unroll
    for (int kh = 0; kh < 3; ++kh) m[kh][t] = cmask * rm[kh];
  }

  float acc[CO_TILE][PIX];
#pragma unroll
  for (int co = 0; co < CO_TILE; ++co) {
    float bv = bias[cobase + co];
#pragma unroll
    for (int j = 0; j < PIX; ++j) acc[co][j] = bv;
  }

  for (int c = 0; c < CIN; ++c) {
    const float* xc = xb + c * (HH * WW);
#pragma unroll
    for (int kh = 0; kh < 3; ++kh) {
      const float* rp = xc + roff[kh];
      float v[6];
#pragma unroll
      for (int t = 0; t < 6; ++t) v[t] = rp[coff[t]] * m[kh][t];
      const float* wp = &sW[(c * 9 + kh * 3) * CO_TILE];
#pragma unroll
      for (int kw = 0; kw < 3; ++kw) {
#pragma unroll
        for (int co = 0; co < CO_TILE; ++co) {
          float wv = wp[kw * CO_TILE + co];
#pragma unroll
          for (int j = 0; j < PIX; ++j)
            acc[co][j] = fmaf(v[kw + j], wv, acc[co][j]);
        }
      }
    }
  }

  float* ob = out + ((size_t)b * COUT + cobase) * (HH * WW) + h * WW + w;
#pragma unroll
  for (int co = 0; co < CO_TILE; ++co) {
    float4 o = make_float4(acc[co][0], acc[co][1], acc[co][2], acc[co][3]);
    *reinterpret_cast<float4*>(ob + co * (HH * WW)) = o;
  }
}

extern "C" void kernel_launch(void* const* d_in, const int* in_sizes, int n_in,
                              void* d_out, int out_size, void* d_ws, size_t ws_size,
                              hipStream_t stream) {
  const float* x = (const float*)d_in[0];
  const float* weight = (const float*)d_in[1];
  const float* bias = (const float*)d_in[2];
  float* out = (float*)d_out;

  // 16*112*112 pixels total per cout-group; 256 threads * 4 pix = 1024/block
  dim3 grid(BATCH * HH * WW / (256 * PIX), COUT / CO_TILE);
  dim3 block(256);
  conv3x3_f32_kernel<<<grid, block, 0, stream>>>(x, weight, bias, out);
}

// Round 5
// 192.495 us; speedup vs baseline: 2.7979x; 2.7979x over previous
//
#include <hip/hip_runtime.h>

// Conv2d 3x3 s1 p1, B=16, CIN=COUT=64, 112x112 — bf16 MFMA implicit-GEMM.
// M=200704 px, N=64 co, K=576 ordered (tap, c). Block=256thr/4 waves, BM=128.
// Wave w owns couts [16w,16w+16), Mrep=8. B-frags (18) persist in VGPRs.
// Per (tap,kc): stage im2col A[128][32] bf16 -> LDS (80B rows), 8x mfma 16x16x32.
// (Resubmission — rounds 3/4 broker timeouts; kernel has not yet run.)

#define CIN   64
#define HH    112
#define WW    112
#define COUT  64
#define HW    (HH*WW)      // 12544
#define CHW   (CIN*HW)     // 802816
#define BM    128
#define LDK   40           // padded A row length (bf16 elems) = 80B

typedef float f32x4 __attribute__((ext_vector_type(4)));
typedef short s16x8 __attribute__((ext_vector_type(8)));
typedef int   s32x4 __attribute__((ext_vector_type(4)));

static __device__ __forceinline__ unsigned short f2bf(float f) {
  unsigned u = __float_as_uint(f);
  u += 0x7fffu + ((u >> 16) & 1u);   // round-to-nearest-even
  return (unsigned short)(u >> 16);
}

__global__ __launch_bounds__(256) void conv_mfma_bf16_kernel(
    const float* __restrict__ x, const float* __restrict__ w,
    const float* __restrict__ bias, float* __restrict__ out) {
  __shared__ __align__(16) unsigned short A[BM * LDK];  // 10240 B

  const int tid  = threadIdx.x;
  const int lane = tid & 63;
  const int wv   = tid >> 6;        // wave id -> co-group
  const int cobase = wv * 16;
  const int col  = lane & 15;       // B: co within group | A-read: pixel row
  const int koct = lane >> 4;       // k-octet 0..3

  const int P0  = blockIdx.x * BM;
  const int b   = P0 / HW;          // uniform per block (128 | 12544)
  const int pr0 = P0 - b * HW;      // pixel offset within image

  // ---- preload 18 B-fragments: k = tap*64 + c ; lane holds co=cobase+col,
  // c = kc*32 + koct*8 + j ; element = weight[(c*9+tap)*64 + co]
  s16x8 bfr[18];
#pragma unroll
  for (int tap = 0; tap < 9; ++tap) {
#pragma unroll
    for (int kc = 0; kc < 2; ++kc) {
      const int c0 = kc * 32 + koct * 8;
      s16x8 v;
#pragma unroll
      for (int j = 0; j < 8; ++j)
        v[j] = (short)f2bf(w[((c0 + j) * 9 + tap) * COUT + cobase + col]);
      bfr[tap * 2 + kc] = v;
    }
  }

  // ---- accumulators (8 M-frags x 4 f32), init with bias[co]
  const float bv = bias[cobase + col];
  f32x4 acc[8];
#pragma unroll
  for (int m = 0; m < 8; ++m) acc[m] = (f32x4){bv, bv, bv, bv};

  // ---- per-thread staging coordinates: 2 (pixel, c-octet) pairs
  int pp[2], poct[2], ph[2], pw[2];
#pragma unroll
  for (int g = 0; g < 2; ++g) {
    const int idx = tid + 256 * g;      // 0..511
    const int p   = idx & (BM - 1);
    poct[g] = idx >> 7;                 // 0..3
    pp[g]   = p;
    const int pr = pr0 + p;
    ph[g] = pr / WW;
    pw[g] = pr - ph[g] * WW;
  }
  const float* xb = x + (size_t)b * CHW;

  // ---- main loop: 9 taps x 2 k-chunks
#pragma unroll
  for (int tap = 0; tap < 9; ++tap) {
    const int dh = tap / 3 - 1, dw = tap - (tap / 3) * 3 - 1;
    int   sp[2];
    bool  val[2];
#pragma unroll
    for (int g = 0; g < 2; ++g) {
      const int y = ph[g] + dh, xc = pw[g] + dw;
      val[g] = ((unsigned)y < (unsigned)HH) && ((unsigned)xc < (unsigned)WW);
      sp[g]  = val[g] ? (y * WW + xc) : 0;
    }
#pragma unroll
    for (int kc = 0; kc < 2; ++kc) {
      __syncthreads();  // previous step's A reads complete
#pragma unroll
      for (int g = 0; g < 2; ++g) {
        const int c0 = kc * 32 + poct[g] * 8;
        const float* src = xb + (size_t)c0 * HW + sp[g];
        unsigned r[4];
#pragma unroll
        for (int jj = 0; jj < 4; ++jj) {
          const float a0 = val[g] ? src[(2 * jj + 0) * HW] : 0.f;
          const float a1 = val[g] ? src[(2 * jj + 1) * HW] : 0.f;
          r[jj] = (unsigned)f2bf(a0) | ((unsigned)f2bf(a1) << 16);
        }
        *(s32x4*)&A[pp[g] * LDK + poct[g] * 8] =
            (s32x4){(int)r[0], (int)r[1], (int)r[2], (int)r[3]};
      }
      __syncthreads();  // A ready
#pragma unroll
      for (int m = 0; m < 8; ++m) {
        const s16x8 af = *(const s16x8*)&A[(m * 16 + col) * LDK + koct * 8];
        acc[m] = __builtin_amdgcn_mfma_f32_16x16x32_bf16(
            af, bfr[tap * 2 + kc], acc[m], 0, 0, 0);
      }
    }
  }

  // ---- store: D row = pixel (m*16 + koct*4 + r), col = cout (cobase+col)
  // out[b][co][pix] ; float4 along pixels -> per-plane coalesced
  float* ob = out + (size_t)b * (COUT * HW) + (size_t)(cobase + col) * HW + pr0;
#pragma unroll
  for (int m = 0; m < 8; ++m)
    *(f32x4*)(ob + m * 16 + koct * 4) = acc[m];
}

extern "C" void kernel_launch(void* const* d_in, const int* in_sizes, int n_in,
                              void* d_out, int out_size, void* d_ws, size_t ws_size,
                              hipStream_t stream) {
  const float* x = (const float*)d_in[0];
  const float* weight = (const float*)d_in[1];
  const float* bias = (const float*)d_in[2];
  float* out = (float*)d_out;

  const int M = 16 * HW;                 // 200704 pixels
  dim3 grid(M / BM);                     // 1568 blocks
  dim3 block(256);
  conv_mfma_bf16_kernel<<<grid, block, 0, stream>>>(x, weight, bias, out);
}

// Round 6
// 147.485 us; speedup vs baseline: 3.6517x; 1.3052x over previous
//
#include <hip/hip_runtime.h>

// Conv2d 3x3 s1 p1, B=16, CIN=COUT=64, 112x112 — bf16 MFMA implicit-GEMM v2.
// Block = 2 output rows x 112 = 224 px (Mrep=14), 4 waves (16 couts each).
// Stage 4-row input halo tile [450 px][40ch-padded] bf16 in LDS once per
// 32-ch chunk; 9 taps = compile-time shifted ds_read_b128. 3 barriers total.
// Row-wrap edges masked on 4 (tap,m) combos. XCD-swizzled grid (896 = 8*112).

#define CIN   64
#define HH    112
#define WW    112
#define COUT  64
#define HW    (HH*WW)      // 12544
#define CHW   (CIN*HW)
#define LDC   40           // padded channel stride (elems) = 80B, 16B-aligned
#define TROWS 450          // 448 tile px + shift(1) + masked overreach(1)

typedef float f32x4 __attribute__((ext_vector_type(4)));
typedef short s16x8 __attribute__((ext_vector_type(8)));
typedef int   s32x4 __attribute__((ext_vector_type(4)));

static __device__ __forceinline__ unsigned short f2bf(float f) {
  unsigned u = __float_as_uint(f);
  u += 0x7fffu + ((u >> 16) & 1u);   // RNE
  return (unsigned short)(u >> 16);
}

__global__ __launch_bounds__(256) void conv_mfma_bf16_v2(
    const float* __restrict__ x, const float* __restrict__ w,
    const float* __restrict__ bias, float* __restrict__ out) {
  __shared__ __align__(16) unsigned short A[TROWS * LDC];  // 36000 B

  const int tid  = threadIdx.x;
  const int lane = tid & 63;
  const int wv   = tid >> 6;        // wave id: co-group AND staging c-octet
  const int cobase = wv * 16;
  const int col  = lane & 15;       // MFMA col: co (B) / pixel-row (A-read)
  const int koct = lane >> 4;       // k-octet 0..3

  // XCD swizzle: 896 blocks, 8 XCDs, 112 consecutive row-pair blocks per XCD
  const int bx0 = blockIdx.x;
  const int bx  = (bx0 & 7) * 112 + (bx0 >> 3);
  const int b   = bx / 56;          // image
  const int r0  = (bx - b * 56) * 2; // first output row
  const int p0  = r0 * WW;

  const float* xb = x + (size_t)b * CHW;

  const float bv = bias[cobase + col];
  f32x4 acc[14];
#pragma unroll
  for (int m = 0; m < 14; ++m) acc[m] = (f32x4){bv, bv, bv, bv};

  const int stage_base = (r0 - 1) * WW;  // + ti = global pixel offset

#pragma unroll
  for (int kc = 0; kc < 2; ++kc) {
    // ---- B fragments for this kc: k = tap*64 + c, c = kc*32 + koct*8 + j
    s16x8 bfr[9];
#pragma unroll
    for (int tap = 0; tap < 9; ++tap) {
      const int c0 = kc * 32 + koct * 8;
      s16x8 v;
#pragma unroll
      for (int j = 0; j < 8; ++j)
        v[j] = (short)f2bf(w[((c0 + j) * 9 + tap) * COUT + cobase + col]);
      bfr[tap] = v;
    }

    if (kc) __syncthreads();  // previous phase's A reads complete

    // ---- stage: wave wv stages its channel-octet; ti = lane + 64*g (0..447)
    const int cbase = kc * 32 + wv * 8;
    const float* src0 = xb + (size_t)cbase * HW;
#pragma unroll
    for (int g = 0; g < 7; ++g) {
      const int ti = lane + 64 * g;
      const int tr = ti / WW;                       // tile row 0..3
      const int gr = r0 - 1 + tr;                   // global input row
      const bool val = (unsigned)gr < (unsigned)HH; // halo rows -> zeros
      const int goff = val ? (stage_base + ti) : 0;
      unsigned rr[4];
#pragma unroll
      for (int jj = 0; jj < 4; ++jj) {
        const float a0 = val ? src0[(size_t)(2 * jj + 0) * HW + goff] : 0.f;
        const float a1 = val ? src0[(size_t)(2 * jj + 1) * HW + goff] : 0.f;
        rr[jj] = (unsigned)f2bf(a0) | ((unsigned)f2bf(a1) << 16);
      }
      *(s32x4*)&A[(ti + 1) * LDC + wv * 8] =
          (s32x4){(int)rr[0], (int)rr[1], (int)rr[2], (int)rr[3]};
    }
    __syncthreads();

    // ---- compute: 9 taps x 14 Mfrags, pure LDS->MFMA
#pragma unroll
    for (int tap = 0; tap < 9; ++tap) {
      const int dh = tap / 3 - 1, dw = tap - (tap / 3) * 3 - 1;
      const int tbase = (dh + 1) * WW + dw + 1;     // +1 = store shift
#pragma unroll
      for (int m = 0; m < 14; ++m) {
        s16x8 af = *(const s16x8*)&A[(m * 16 + col + tbase) * LDC + koct * 8];
        // w+dw out of [0,112): only m%7==0/col0 (dw=-1), m%7==6/col15 (dw=+1)
        if (dw == -1 && (m % 7) == 0) {
          if (col == 0) af = (s16x8){0, 0, 0, 0, 0, 0, 0, 0};
        }
        if (dw == 1 && (m % 7) == 6) {
          if (col == 15) af = (s16x8){0, 0, 0, 0, 0, 0, 0, 0};
        }
        acc[m] = __builtin_amdgcn_mfma_f32_16x16x32_bf16(af, bfr[tap],
                                                         acc[m], 0, 0, 0);
      }
    }
  }

  // ---- store: pixel = p0 + m*16 + koct*4 + r, cout = cobase + col
  float* ob = out + (size_t)b * (COUT * HW) + (size_t)(cobase + col) * HW + p0;
#pragma unroll
  for (int m = 0; m < 14; ++m)
    *(f32x4*)(ob + m * 16 + koct * 4) = acc[m];
}

extern "C" void kernel_launch(void* const* d_in, const int* in_sizes, int n_in,
                              void* d_out, int out_size, void* d_ws, size_t ws_size,
                              hipStream_t stream) {
  const float* x = (const float*)d_in[0];
  const float* weight = (const float*)d_in[1];
  const float* bias = (const float*)d_in[2];
  float* out = (float*)d_out;

  dim3 grid(16 * 56);   // 896 blocks = 16 images x 56 row-pairs
  dim3 block(256);
  conv_mfma_bf16_v2<<<grid, block, 0, stream>>>(x, weight, bias, out);
}

// Round 7
// 136.916 us; speedup vs baseline: 3.9336x; 1.0772x over previous
//
#include <hip/hip_runtime.h>

// Conv2d 3x3 s1 p1, B=16, CIN=COUT=64, 112x112 — bf16 MFMA implicit-GEMM v3.
// Occupancy/TLP round: 1-row tiles (grid 1792 = 16 img x 112 rows, Mrep=7),
// __launch_bounds__(256,4) caps VGPR<=128 (4 blocks/CU), float2 staging.
// LDS: 3-row halo tile [338][40] bf16 = 27 KB. 3 barriers per block.

#define CIN   64
#define HH    112
#define WW    112
#define COUT  64
#define HW    (HH*WW)      // 12544
#define CHW   (CIN*HW)
#define LDC   40           // padded channel stride (elems) = 80B
#define TROWS 338          // 336 staged px + edge slots 0/337 (masked reads)

typedef float f32x4 __attribute__((ext_vector_type(4)));
typedef short s16x8 __attribute__((ext_vector_type(8)));
typedef int   s32x4 __attribute__((ext_vector_type(4)));

static __device__ __forceinline__ unsigned short f2bf(float f) {
  unsigned u = __float_as_uint(f);
  u += 0x7fffu + ((u >> 16) & 1u);   // RNE
  return (unsigned short)(u >> 16);
}

__global__ __launch_bounds__(256, 4) void conv_mfma_bf16_v3(
    const float* __restrict__ x, const float* __restrict__ w,
    const float* __restrict__ bias, float* __restrict__ out) {
  __shared__ __align__(16) unsigned short A[TROWS * LDC];  // 27040 B

  const int tid  = threadIdx.x;
  const int lane = tid & 63;
  const int wv   = tid >> 6;        // wave id: co-group AND staging c-octet
  const int cobase = wv * 16;
  const int col  = lane & 15;
  const int koct = lane >> 4;

  // XCD swizzle: 1792 = 8 * 224; consecutive rows of an image share an XCD L2
  const int bx0 = blockIdx.x;
  const int bx  = (bx0 & 7) * 224 + (bx0 >> 3);
  const int b   = bx / 112;           // image
  const int r0  = bx - b * 112;       // output row
  const int p0  = r0 * WW;

  const float* xb = x + (size_t)b * CHW;

  const float bv = bias[cobase + col];
  f32x4 acc[7];
#pragma unroll
  for (int m = 0; m < 7; ++m) acc[m] = (f32x4){bv, bv, bv, bv};

  const int stage_base = (r0 - 1) * WW;

#pragma unroll
  for (int kc = 0; kc < 2; ++kc) {
    // B fragments: k = tap*64 + c, c = kc*32 + koct*8 + j
    s16x8 bfr[9];
#pragma unroll
    for (int tap = 0; tap < 9; ++tap) {
      const int c0 = kc * 32 + koct * 8;
      s16x8 v;
#pragma unroll
      for (int j = 0; j < 8; ++j)
        v[j] = (short)f2bf(w[((c0 + j) * 9 + tap) * COUT + cobase + col]);
      bfr[tap] = v;
    }

    if (kc) __syncthreads();  // previous phase's A reads complete

    // Stage 3 input rows x 8 channels (this wave's octet), float2 px pairs.
    // 112 is even -> a pair never crosses a row boundary.
    const int cbase = kc * 32 + wv * 8;
    const float* src0 = xb + (size_t)cbase * HW;
#pragma unroll
    for (int g = 0; g < 3; ++g) {
      const int pi = lane + 64 * g;           // pixel-pair index
      if (pi < 168) {
        const int px0 = 2 * pi;               // tile px 0..334
        const int tr  = px0 / WW;             // tile row 0..2
        const int gr  = r0 - 1 + tr;
        const bool val = (unsigned)gr < (unsigned)HH;
        const int goff = val ? (stage_base + px0) : 0;
        float2 v[8];
#pragma unroll
        for (int j = 0; j < 8; ++j)
          v[j] = val ? *(const float2*)(src0 + (size_t)j * HW + goff)
                     : make_float2(0.f, 0.f);
        unsigned ra[4], rb[4];
#pragma unroll
        for (int jp = 0; jp < 4; ++jp) {
          ra[jp] = (unsigned)f2bf(v[2 * jp].x) | ((unsigned)f2bf(v[2 * jp + 1].x) << 16);
          rb[jp] = (unsigned)f2bf(v[2 * jp].y) | ((unsigned)f2bf(v[2 * jp + 1].y) << 16);
        }
        *(s32x4*)&A[(px0 + 1) * LDC + wv * 8] =
            (s32x4){(int)ra[0], (int)ra[1], (int)ra[2], (int)ra[3]};
        *(s32x4*)&A[(px0 + 2) * LDC + wv * 8] =
            (s32x4){(int)rb[0], (int)rb[1], (int)rb[2], (int)rb[3]};
      }
    }
    __syncthreads();

    // Compute: 9 taps x 7 Mfrags, pure LDS->MFMA
#pragma unroll
    for (int tap = 0; tap < 9; ++tap) {
      const int dh = tap / 3 - 1, dw = tap - (tap / 3) * 3 - 1;
      const int tbase = (dh + 1) * WW + dw + 1;
#pragma unroll
      for (int m = 0; m < 7; ++m) {
        s16x8 af = *(const s16x8*)&A[(m * 16 + col + tbase) * LDC + koct * 8];
        if (dw == -1 && m == 0 && col == 0) af = (s16x8){0,0,0,0,0,0,0,0};
        if (dw ==  1 && m == 6 && col == 15) af = (s16x8){0,0,0,0,0,0,0,0};
        acc[m] = __builtin_amdgcn_mfma_f32_16x16x32_bf16(af, bfr[tap],
                                                         acc[m], 0, 0, 0);
      }
    }
  }

  // Store: pixel = p0 + m*16 + koct*4 + r, cout = cobase + col
  float* ob = out + (size_t)b * (COUT * HW) + (size_t)(cobase + col) * HW + p0;
#pragma unroll
  for (int m = 0; m < 7; ++m)
    *(f32x4*)(ob + m * 16 + koct * 4) = acc[m];
}

extern "C" void kernel_launch(void* const* d_in, const int* in_sizes, int n_in,
                              void* d_out, int out_size, void* d_ws, size_t ws_size,
                              hipStream_t stream) {
  const float* x = (const float*)d_in[0];
  const float* weight = (const float*)d_in[1];
  const float* bias = (const float*)d_in[2];
  float* out = (float*)d_out;

  dim3 grid(16 * 112);   // 1792 blocks = 16 images x 112 rows
  dim3 block(256);
  conv_mfma_bf16_v3<<<grid, block, 0, stream>>>(x, weight, bias, out);
}